// Round 1
// baseline (123.117 us; speedup 1.0000x reference)
//
#include <hip/hip_runtime.h>

// Problem constants
#define B 16
#define Z 64
#define U 8
#define P 128
#define X 64
#define H 128
#define BZU (B * Z * U)   // 8192

__device__ __forceinline__ float elu1(float v) {
    return v > 0.0f ? v : (expf(v) - 1.0f);
}

// One block per batch row b (16 blocks, 128 threads). Computes phi[b, 0:128].
__global__ __launch_bounds__(128) void encoder_kernel(
    const float* __restrict__ x,
    const float* __restrict__ W1, const float* __restrict__ b1,
    const float* __restrict__ W2, const float* __restrict__ b2,
    const float* __restrict__ W3, const float* __restrict__ b3,
    const float* __restrict__ W4, const float* __restrict__ b4,
    float* __restrict__ phi) {
    __shared__ float xs[X];
    __shared__ float hs[H];
    const int b = blockIdx.x;
    const int j = threadIdx.x;

    if (j < X) xs[j] = x[b * X + j];
    __syncthreads();

    // layer 1: (X) -> (H)
    float v = b1[j];
    #pragma unroll 8
    for (int k = 0; k < X; ++k) v = fmaf(xs[k], W1[k * H + j], v);
    hs[j] = elu1(v);
    __syncthreads();

    // layer 2: (H) -> (H)
    v = b2[j];
    #pragma unroll 8
    for (int k = 0; k < H; ++k) v = fmaf(hs[k], W2[k * H + j], v);
    __syncthreads();
    hs[j] = elu1(v);
    __syncthreads();

    // layer 3: (H) -> (H)
    v = b3[j];
    #pragma unroll 8
    for (int k = 0; k < H; ++k) v = fmaf(hs[k], W3[k * H + j], v);
    __syncthreads();
    hs[j] = elu1(v);
    __syncthreads();

    // layer 4: (H) -> (P), no activation
    v = b4[j];
    #pragma unroll 8
    for (int k = 0; k < H; ++k) v = fmaf(hs[k], W4[k * P + j], v);
    phi[b * P + j] = v;
}

// One block per (b,z,u). Streams the 128x128 Linv matrix once (64 KB),
// computes mu = phi^T L q  and  sig = phi^T L phi  in a single pass.
__global__ __launch_bounds__(256) void bilinear_kernel(
    const float* __restrict__ Linv,
    const float* __restrict__ Q,
    const float* __restrict__ phi,
    const float* __restrict__ logSigEps,
    float* __restrict__ out_mu,
    float* __restrict__ out_cov) {
    __shared__ float phis[P];
    __shared__ float qs[P];
    __shared__ float rmu[4];
    __shared__ float rsg[4];

    const int m = blockIdx.x;          // 0 .. BZU-1
    const int b = m >> 9;              // / (Z*U) = 512
    const int u = m & 7;               // U = 8
    const int t = threadIdx.x;

    if (t < P)            phis[t]    = phi[b * P + t];
    else if (t < 2 * P)   qs[t - P]  = Q[(size_t)m * P + (t - P)];
    __syncthreads();

    // Column factors are constant per thread: float4 index v = t + 256k,
    // col group = v & 31 = t & 31 for all k.
    const int j4 = (t & 31) * 4;
    const float q0 = qs[j4 + 0], q1 = qs[j4 + 1], q2 = qs[j4 + 2], q3 = qs[j4 + 3];
    const float p0 = phis[j4 + 0], p1 = phis[j4 + 1], p2 = phis[j4 + 2], p3 = phis[j4 + 3];
    const int r0 = t >> 5;             // row = r0 + 8k

    const float4* __restrict__ Lp =
        (const float4*)(Linv + (size_t)m * (P * P));

    float mu_acc = 0.0f, sg_acc = 0.0f;
    #pragma unroll
    for (int k = 0; k < 16; ++k) {
        const float4 L = Lp[t + 256 * k];
        const float pi = phis[r0 + 8 * k];       // LDS broadcast within 32-group
        const float dq = L.x * q0 + L.y * q1 + L.z * q2 + L.w * q3;
        const float dp = L.x * p0 + L.y * p1 + L.z * p2 + L.w * p3;
        mu_acc = fmaf(pi, dq, mu_acc);
        sg_acc = fmaf(pi, dp, sg_acc);
    }

    // Reduce across the wave (64 lanes)
    #pragma unroll
    for (int off = 32; off > 0; off >>= 1) {
        mu_acc += __shfl_down(mu_acc, off, 64);
        sg_acc += __shfl_down(sg_acc, off, 64);
    }
    const int wave = t >> 6;
    const int lane = t & 63;
    if (lane == 0) { rmu[wave] = mu_acc; rsg[wave] = sg_acc; }
    __syncthreads();

    if (t == 0) {
        const float mu = rmu[0] + rmu[1] + rmu[2] + rmu[3];
        const float sg = rsg[0] + rsg[1] + rsg[2] + rsg[3];
        out_mu[m]  = mu;
        out_cov[m] = expf(logSigEps[u]) * (1.0f + sg);
    }
}

extern "C" void kernel_launch(void* const* d_in, const int* in_sizes, int n_in,
                              void* d_out, int out_size, void* d_ws, size_t ws_size,
                              hipStream_t stream) {
    const float* x        = (const float*)d_in[0];
    const float* Linv     = (const float*)d_in[1];
    const float* Q        = (const float*)d_in[2];
    const float* W1       = (const float*)d_in[3];
    const float* b1       = (const float*)d_in[4];
    const float* W2       = (const float*)d_in[5];
    const float* b2       = (const float*)d_in[6];
    const float* W3       = (const float*)d_in[7];
    const float* b3       = (const float*)d_in[8];
    const float* W4       = (const float*)d_in[9];
    const float* b4       = (const float*)d_in[10];
    const float* logSigEps= (const float*)d_in[11];

    float* phi = (float*)d_ws;                  // 16*128 floats = 8 KB
    float* out_mu  = (float*)d_out;             // first 8192 floats: mu (B,Z,U,1)
    float* out_cov = (float*)d_out + BZU;       // next 8192 floats: pred_cov_diag

    encoder_kernel<<<B, H, 0, stream>>>(x, W1, b1, W2, b2, W3, b3, W4, b4, phi);
    bilinear_kernel<<<BZU, 256, 0, stream>>>(Linv, Q, phi, logSigEps, out_mu, out_cov);
}

// Round 2
// 94.858 us; speedup vs baseline: 1.2979x; 1.2979x over previous
//
#include <hip/hip_runtime.h>

// Problem constants
#define B 16
#define Z 64
#define U 8
#define P 128
#define X 64
#define H 128
#define BZU (B * Z * U)   // 8192

typedef float f32x4 __attribute__((ext_vector_type(4)));

__device__ __forceinline__ float elu1(float v) {
    return v > 0.0f ? v : (expf(v) - 1.0f);
}

// One block per batch row b (16 blocks, 256 threads; 2 threads per output
// neuron, each summing half the k-range, combined through LDS).
__global__ __launch_bounds__(256) void encoder_kernel(
    const float* __restrict__ x,
    const float* __restrict__ W1, const float* __restrict__ b1,
    const float* __restrict__ W2, const float* __restrict__ b2,
    const float* __restrict__ W3, const float* __restrict__ b3,
    const float* __restrict__ W4, const float* __restrict__ b4,
    float* __restrict__ phi) {
    __shared__ float xs[X];
    __shared__ float hs[H];
    __shared__ float ps[2][H];
    const int b    = blockIdx.x;
    const int t    = threadIdx.x;
    const int j    = t & (H - 1);      // output neuron
    const int half = t >> 7;           // 0 or 1

    if (t < X) xs[t] = x[b * X + t];
    __syncthreads();

    // layer 1: (X=64) -> (H=128); each half sums 32 k's
    {
        float v = 0.0f;
        const int k0 = half * 32;
        #pragma unroll 8
        for (int k = k0; k < k0 + 32; ++k) v = fmaf(xs[k], W1[k * H + j], v);
        ps[half][j] = v;
    }
    __syncthreads();
    if (t < H) hs[j] = elu1(b1[j] + ps[0][j] + ps[1][j]);
    __syncthreads();

    // layer 2: (H) -> (H); each half sums 64 k's
    {
        float v = 0.0f;
        const int k0 = half * 64;
        #pragma unroll 8
        for (int k = k0; k < k0 + 64; ++k) v = fmaf(hs[k], W2[k * H + j], v);
        ps[half][j] = v;
    }
    __syncthreads();
    if (t < H) hs[j] = elu1(b2[j] + ps[0][j] + ps[1][j]);
    __syncthreads();

    // layer 3
    {
        float v = 0.0f;
        const int k0 = half * 64;
        #pragma unroll 8
        for (int k = k0; k < k0 + 64; ++k) v = fmaf(hs[k], W3[k * H + j], v);
        ps[half][j] = v;
    }
    __syncthreads();
    if (t < H) hs[j] = elu1(b3[j] + ps[0][j] + ps[1][j]);
    __syncthreads();

    // layer 4: (H) -> (P), no activation
    {
        float v = 0.0f;
        const int k0 = half * 64;
        #pragma unroll 8
        for (int k = k0; k < k0 + 64; ++k) v = fmaf(hs[k], W4[k * P + j], v);
        ps[half][j] = v;
    }
    __syncthreads();
    if (t < H) phi[b * P + j] = b4[j] + ps[0][j] + ps[1][j];
}

// One block per (b,z,u). Streams the 128x128 Linv matrix once (64 KB, nt),
// computes mu = phi^T L q  and  sig = phi^T L phi  in a single pass.
__global__ __launch_bounds__(256) void bilinear_kernel(
    const float* __restrict__ Linv,
    const float* __restrict__ Q,
    const float* __restrict__ phi,
    const float* __restrict__ logSigEps,
    float* __restrict__ out_mu,
    float* __restrict__ out_cov) {
    __shared__ float phis[P];
    __shared__ float qs[P];
    __shared__ float rmu[4];
    __shared__ float rsg[4];

    const int m = blockIdx.x;          // 0 .. BZU-1
    const int b = m >> 9;              // / (Z*U) = 512
    const int u = m & 7;               // U = 8
    const int t = threadIdx.x;

    if (t < P)            phis[t]    = phi[b * P + t];
    else if (t < 2 * P)   qs[t - P]  = Q[(size_t)m * P + (t - P)];
    __syncthreads();

    // Column factors are constant per thread: float4 index v = t + 256k,
    // col group = v & 31 = t & 31 for all k.
    const int j4 = (t & 31) * 4;
    const float q0 = qs[j4 + 0], q1 = qs[j4 + 1], q2 = qs[j4 + 2], q3 = qs[j4 + 3];
    const float p0 = phis[j4 + 0], p1 = phis[j4 + 1], p2 = phis[j4 + 2], p3 = phis[j4 + 3];
    const int r0 = t >> 5;             // row = r0 + 8k

    // Hoist ALL LDS reads out of the streaming loop so the 16 global loads
    // have no lgkmcnt interleave and can all be issued up front.
    float pi[16];
    #pragma unroll
    for (int k = 0; k < 16; ++k) pi[k] = phis[r0 + 8 * k];

    const f32x4* __restrict__ Lp =
        (const f32x4*)(Linv + (size_t)m * (P * P));

    float mu_acc = 0.0f, sg_acc = 0.0f;
    #pragma unroll
    for (int k = 0; k < 16; ++k) {
        const f32x4 L = __builtin_nontemporal_load(Lp + t + 256 * k);
        const float dq = L[0] * q0 + L[1] * q1 + L[2] * q2 + L[3] * q3;
        const float dp = L[0] * p0 + L[1] * p1 + L[2] * p2 + L[3] * p3;
        mu_acc = fmaf(pi[k], dq, mu_acc);
        sg_acc = fmaf(pi[k], dp, sg_acc);
    }

    // Reduce across the wave (64 lanes)
    #pragma unroll
    for (int off = 32; off > 0; off >>= 1) {
        mu_acc += __shfl_down(mu_acc, off, 64);
        sg_acc += __shfl_down(sg_acc, off, 64);
    }
    const int wave = t >> 6;
    const int lane = t & 63;
    if (lane == 0) { rmu[wave] = mu_acc; rsg[wave] = sg_acc; }
    __syncthreads();

    if (t == 0) {
        const float mu = rmu[0] + rmu[1] + rmu[2] + rmu[3];
        const float sg = rsg[0] + rsg[1] + rsg[2] + rsg[3];
        out_mu[m]  = mu;
        out_cov[m] = expf(logSigEps[u]) * (1.0f + sg);
    }
}

extern "C" void kernel_launch(void* const* d_in, const int* in_sizes, int n_in,
                              void* d_out, int out_size, void* d_ws, size_t ws_size,
                              hipStream_t stream) {
    const float* x        = (const float*)d_in[0];
    const float* Linv     = (const float*)d_in[1];
    const float* Q        = (const float*)d_in[2];
    const float* W1       = (const float*)d_in[3];
    const float* b1       = (const float*)d_in[4];
    const float* W2       = (const float*)d_in[5];
    const float* b2       = (const float*)d_in[6];
    const float* W3       = (const float*)d_in[7];
    const float* b3       = (const float*)d_in[8];
    const float* W4       = (const float*)d_in[9];
    const float* b4       = (const float*)d_in[10];
    const float* logSigEps= (const float*)d_in[11];

    float* phi = (float*)d_ws;                  // 16*128 floats = 8 KB
    float* out_mu  = (float*)d_out;             // first 8192 floats: mu (B,Z,U,1)
    float* out_cov = (float*)d_out + BZU;       // next 8192 floats: pred_cov_diag

    encoder_kernel<<<B, 256, 0, stream>>>(x, W1, b1, W2, b2, W3, b3, W4, b4, phi);
    bilinear_kernel<<<BZU, 256, 0, stream>>>(Linv, Q, phi, logSigEps, out_mu, out_cov);
}

// Round 3
// 93.526 us; speedup vs baseline: 1.3164x; 1.0142x over previous
//
#include <hip/hip_runtime.h>

// Problem constants
#define B 16
#define Z 64
#define U 8
#define P 128
#define X 64
#define H 128
#define BZU (B * Z * U)       // 8192
#define BLOCKS 1024
#define M_PER_BLOCK (BZU / BLOCKS)   // 8 matrices per block, 2 per wave

typedef float f32x4 __attribute__((ext_vector_type(4)));

__device__ __forceinline__ float elu1(float v) {
    return v > 0.0f ? v : (expf(v) - 1.0f);
}

// Single fused kernel. Each block:
//  1) redundantly computes phi[b] for its batch row into LDS (cheap: weights
//     are L2-hot, total redundant VALU ~1.5 us hidden under the HBM stream);
//  2) each wave independently streams 2 full 128x128 Linv matrices (nt loads)
//     and reduces mu / sigma with pure wave shuffles -- no barriers in the
//     stream phase, so no vmcnt-draining syncthreads bubbles.
__global__ __launch_bounds__(256) void fused_kernel(
    const float* __restrict__ x,
    const float* __restrict__ Linv,
    const float* __restrict__ Q,
    const float* __restrict__ W1, const float* __restrict__ b1,
    const float* __restrict__ W2, const float* __restrict__ b2,
    const float* __restrict__ W3, const float* __restrict__ b3,
    const float* __restrict__ W4, const float* __restrict__ b4,
    const float* __restrict__ logSigEps,
    float* __restrict__ out_mu,
    float* __restrict__ out_cov)
{
    __shared__ float xs[X];
    __shared__ float hs[H];
    __shared__ float ps[2][H];
    __shared__ float phis[P];

    const int blk  = blockIdx.x;
    const int t    = threadIdx.x;
    const int b    = blk >> 6;         // 1024 blocks / 16 batch rows = 64
    const int j    = t & (H - 1);
    const int half = t >> 7;

    // ---- encoder (split-k over 2 halves, combined via LDS) ----
    if (t < X) xs[t] = x[b * X + t];
    __syncthreads();

    { // layer 1: X=64 -> H
        float v = 0.0f; const int k0 = half * 32;
        #pragma unroll 8
        for (int k = k0; k < k0 + 32; ++k) v = fmaf(xs[k], W1[k * H + j], v);
        ps[half][j] = v;
    }
    __syncthreads();
    if (t < H) hs[j] = elu1(b1[j] + ps[0][j] + ps[1][j]);
    __syncthreads();

    { // layer 2
        float v = 0.0f; const int k0 = half * 64;
        #pragma unroll 8
        for (int k = k0; k < k0 + 64; ++k) v = fmaf(hs[k], W2[k * H + j], v);
        ps[half][j] = v;
    }
    __syncthreads();
    if (t < H) hs[j] = elu1(b2[j] + ps[0][j] + ps[1][j]);
    __syncthreads();

    { // layer 3
        float v = 0.0f; const int k0 = half * 64;
        #pragma unroll 8
        for (int k = k0; k < k0 + 64; ++k) v = fmaf(hs[k], W3[k * H + j], v);
        ps[half][j] = v;
    }
    __syncthreads();
    if (t < H) hs[j] = elu1(b3[j] + ps[0][j] + ps[1][j]);
    __syncthreads();

    { // layer 4: H -> P, no activation
        float v = 0.0f; const int k0 = half * 64;
        #pragma unroll 8
        for (int k = k0; k < k0 + 64; ++k) v = fmaf(hs[k], W4[k * P + j], v);
        ps[half][j] = v;
    }
    __syncthreads();
    if (t < H) phis[j] = b4[j] + ps[0][j] + ps[1][j];
    __syncthreads();

    // ---- wave-independent bilinear stream ----
    const int wave = t >> 6;
    const int lane = t & 63;
    // float4 index v = lane + 64k -> column group v&31 == lane&31, constant.
    const int j4 = (lane & 31) * 4;
    const int r0 = lane >> 5;          // row = r0 + 2k

    const float pp0 = phis[j4 + 0], pp1 = phis[j4 + 1],
                pp2 = phis[j4 + 2], pp3 = phis[j4 + 3];

    #pragma unroll
    for (int i = 0; i < M_PER_BLOCK / 4; ++i) {   // 2 matrices per wave
        const int m = blk * M_PER_BLOCK + wave * (M_PER_BLOCK / 4) + i;
        const float4 qv = *(const float4*)(Q + (size_t)m * P + j4);
        const f32x4* __restrict__ Lp =
            (const f32x4*)Linv + (size_t)m * (P * P / 4);

        float mu = 0.0f, sg = 0.0f;
        #pragma unroll
        for (int c = 0; c < 4; ++c) {
            // issue the whole 16-load chunk before any consumption
            f32x4 Lb[16];
            #pragma unroll
            for (int k2 = 0; k2 < 16; ++k2)
                Lb[k2] = __builtin_nontemporal_load(Lp + lane + 64 * (16 * c + k2));
            float pi[16];
            #pragma unroll
            for (int k2 = 0; k2 < 16; ++k2) pi[k2] = phis[r0 + 32 * c + 2 * k2];
            #pragma unroll
            for (int k2 = 0; k2 < 16; ++k2) {
                const f32x4 L = Lb[k2];
                const float dq = L[0] * qv.x + L[1] * qv.y + L[2] * qv.z + L[3] * qv.w;
                const float dp = L[0] * pp0 + L[1] * pp1 + L[2] * pp2 + L[3] * pp3;
                mu = fmaf(pi[k2], dq, mu);
                sg = fmaf(pi[k2], dp, sg);
            }
        }

        #pragma unroll
        for (int off = 32; off > 0; off >>= 1) {
            mu += __shfl_down(mu, off, 64);
            sg += __shfl_down(sg, off, 64);
        }
        if (lane == 0) {
            out_mu[m]  = mu;
            out_cov[m] = expf(logSigEps[m & (U - 1)]) * (1.0f + sg);
        }
    }
}

extern "C" void kernel_launch(void* const* d_in, const int* in_sizes, int n_in,
                              void* d_out, int out_size, void* d_ws, size_t ws_size,
                              hipStream_t stream) {
    const float* x        = (const float*)d_in[0];
    const float* Linv     = (const float*)d_in[1];
    const float* Q        = (const float*)d_in[2];
    const float* W1       = (const float*)d_in[3];
    const float* b1       = (const float*)d_in[4];
    const float* W2       = (const float*)d_in[5];
    const float* b2       = (const float*)d_in[6];
    const float* W3       = (const float*)d_in[7];
    const float* b3       = (const float*)d_in[8];
    const float* W4       = (const float*)d_in[9];
    const float* b4       = (const float*)d_in[10];
    const float* logSigEps= (const float*)d_in[11];

    float* out_mu  = (float*)d_out;           // (B,Z,U,1) flat: 8192
    float* out_cov = (float*)d_out + BZU;     // (B,Z,U)   flat: 8192

    fused_kernel<<<BLOCKS, 256, 0, stream>>>(
        x, Linv, Q, W1, b1, W2, b2, W3, b3, W4, b4, logSigEps,
        out_mu, out_cov);
}